// Round 8
// baseline (212.671 us; speedup 1.0000x reference)
//
#include <hip/hip_runtime.h>
#include <math.h>

#define SEQ   2048
#define HDIM  1024
#define NH    16
#define DH    64
#define MTOT  4096   // B*S
#define BHTOT 32     // B*NH

typedef _Float16 half_t;
typedef __attribute__((ext_vector_type(2))) __fp16 fp16x2;
typedef __attribute__((ext_vector_type(4))) _Float16 half4;
typedef __attribute__((ext_vector_type(8))) _Float16 half8;
typedef __attribute__((ext_vector_type(4))) float float4v;

// async global->LDS DMA, 16 B per lane; LDS dest = wave-uniform base + lane*16
typedef __attribute__((address_space(1))) const unsigned int guint;
typedef __attribute__((address_space(3))) unsigned int luint;
__device__ __forceinline__ void glds16(const half_t* g, half_t* l) {
    __builtin_amdgcn_global_load_lds((guint*)g, (luint*)l, 16, 0, 0);
}

// ---------------- fused prologue: 5 fp32->fp16 casts + rope table ----------------
__global__ __launch_bounds__(256)
void prep(const float* __restrict__ x,  const float* __restrict__ wq,
          const float* __restrict__ wk, const float* __restrict__ wv,
          const float* __restrict__ wo,
          half_t* __restrict__ xh,  half_t* __restrict__ wqh,
          half_t* __restrict__ wkh, half_t* __restrict__ wvh,
          half_t* __restrict__ woh, float2* __restrict__ rope)
{
    const int bid = blockIdx.x;
    if (bid < 8192) {
        int i = bid * 256 + threadIdx.x;
        const float* s; half_t* d;
        if (i < 1048576) { s = x; d = xh; }
        else {
            int j = i - 1048576;
            int w = j >> 18; i = j & 262143;
            s = (w == 0) ? wq : (w == 1) ? wk : (w == 2) ? wv : wo;
            d = (w == 0) ? wqh : (w == 1) ? wkh : (w == 2) ? wvh : woh;
        }
        float4 v = ((const float4*)s)[i];
        union { half_t h[4]; uint2 u; } tmp;
        tmp.h[0] = (half_t)v.x; tmp.h[1] = (half_t)v.y;
        tmp.h[2] = (half_t)v.z; tmp.h[3] = (half_t)v.w;
        ((uint2*)d)[i] = tmp.u;
    } else {
        int tt = (bid - 8192) * 256 + threadIdx.x;   // 0 .. SEQ*32-1
        int s = tt >> 5, j = tt & 31;
        float inv = powf(10000.0f, -(float)j / 32.0f);
        float ang = (float)s * inv;
        rope[tt] = make_float2(cosf(ang), sinf(ang));
    }
}

// ---------------- GEMM: C = A(4096x1024,f16) * W^T(1024x1024,f16) ----------------
// m97 structure: global_load_lds width-16 staging, unpadded [128][32] LDS.
__global__ __launch_bounds__(256)
void gemm_qkv(const half_t* __restrict__ A,
              const half_t* __restrict__ w0, const half_t* __restrict__ w1,
              const half_t* __restrict__ w2,
              half_t* __restrict__ Qb, half_t* __restrict__ Kb,
              half_t* __restrict__ Vtb, float* __restrict__ outF,
              const float2* __restrict__ rope, int mode_base)
{
    const int mode = mode_base + blockIdx.z;
    const half_t* Bw = (mode == 1) ? w1 : (mode == 2) ? w2 : w0;

    __shared__ __align__(16) half_t Ash[128][32];
    __shared__ __align__(16) half_t Bsh[128][32];

    const int t    = threadIdx.x;
    const int lane = t & 63;
    const int wave = t >> 6;
    const int quad = lane >> 4;
    const int l16  = lane & 15;
    const int wr   = (wave >> 1) * 64;
    const int wc   = (wave & 1) * 64;
    const int bm   = blockIdx.x, bn = blockIdx.y;

    const int srow = lane >> 2, spos = lane & 3;
    const half_t* Asrc0 = A  + (size_t)(bm * 128 + wave * 32      + srow) * HDIM + spos * 8;
    const half_t* Asrc1 = A  + (size_t)(bm * 128 + wave * 32 + 16 + srow) * HDIM + spos * 8;
    const half_t* Bsrc0 = Bw + (size_t)(bn * 128 + wave * 32      + srow) * HDIM + spos * 8;
    const half_t* Bsrc1 = Bw + (size_t)(bn * 128 + wave * 32 + 16 + srow) * HDIM + spos * 8;
    half_t* Adst0 = &Ash[wave * 32][0];
    half_t* Adst1 = &Ash[wave * 32 + 16][0];
    half_t* Bdst0 = &Bsh[wave * 32][0];
    half_t* Bdst1 = &Bsh[wave * 32 + 16][0];

    float4v acc[4][4] = {};

    for (int kt = 0; kt < HDIM / 32; ++kt) {
        glds16(Asrc0, Adst0);
        glds16(Asrc1, Adst1);
        glds16(Bsrc0, Bdst0);
        glds16(Bsrc1, Bdst1);
        Asrc0 += 32; Asrc1 += 32; Bsrc0 += 32; Bsrc1 += 32;
        __syncthreads();
        half8 af[4], bf[4];
#pragma unroll
        for (int mb = 0; mb < 4; ++mb) af[mb] = *(const half8*)&Ash[wr + mb * 16 + l16][quad * 8];
#pragma unroll
        for (int nb = 0; nb < 4; ++nb) bf[nb] = *(const half8*)&Bsh[wc + nb * 16 + l16][quad * 8];
#pragma unroll
        for (int mb = 0; mb < 4; ++mb)
#pragma unroll
            for (int nb = 0; nb < 4; ++nb)
                acc[mb][nb] = __builtin_amdgcn_mfma_f32_16x16x32_f16(af[mb], bf[nb], acc[mb][nb], 0, 0, 0);
        __syncthreads();
    }

    if (mode == 3) {
#pragma unroll
        for (int mb = 0; mb < 4; ++mb)
#pragma unroll
            for (int nb = 0; nb < 4; ++nb) {
                int row0 = bm * 128 + wr + mb * 16 + quad * 4;
                int col  = bn * 128 + wc + nb * 16 + l16;
#pragma unroll
                for (int r = 0; r < 4; ++r)
                    outF[(size_t)(row0 + r) * HDIM + col] = acc[mb][nb][r];
            }
        return;
    }
    if (mode == 2) {  // V, transposed store: Vtb[bh][d][s]
#pragma unroll
        for (int mb = 0; mb < 4; ++mb)
#pragma unroll
            for (int nb = 0; nb < 4; ++nb) {
                int row0 = bm * 128 + wr + mb * 16 + quad * 4;
                int col  = bn * 128 + wc + nb * 16 + l16;
                int b = row0 >> 11, s0 = row0 & 2047;
                int h = col >> 6,  dd = col & 63;
                union { half_t h4[4]; uint2 u; } tmp;
#pragma unroll
                for (int r = 0; r < 4; ++r) tmp.h4[r] = (half_t)acc[mb][nb][r];
                *(uint2*)&Vtb[((size_t)((b * NH + h) * DH + dd)) * SEQ + s0] = tmp.u;
            }
        return;
    }
    // mode 0 (Q: rope + scale) / mode 1 (K: rope)
    {
        half_t* Ob = (mode == 0) ? Qb : Kb;
        const float scl = (mode == 0) ? 0.125f * 1.44269504088896f : 1.0f;
#pragma unroll
        for (int mb = 0; mb < 4; ++mb)
#pragma unroll
            for (int nb = 0; nb < 4; ++nb) {
                int row0 = bm * 128 + wr + mb * 16 + quad * 4;
                int col  = bn * 128 + wc + nb * 16 + l16;
                int b = row0 >> 11;
                int h = col >> 6, dd = col & 63, j = dd >> 1;
#pragma unroll
                for (int r = 0; r < 4; ++r) {
                    float v  = acc[mb][nb][r];
                    float vp = __shfl_xor(v, 1, 64);   // partner column (col^1)
                    int s = (row0 + r) & 2047;
                    float2 cs = rope[s * 32 + j];
                    float res = ((col & 1) == 0) ? (v * cs.x - vp * cs.y)
                                                 : (vp * cs.y + v * cs.x);
                    Ob[((size_t)((b * NH + h) * SEQ + s)) * DH + dd] = (half_t)(res * scl);
                }
            }
    }
}

// ---------------- fused attention ----------------
// Reference semantics: softmax over ALL keys, THEN causal zeroing, NO renorm.
// S^T = K*Q^T; P^T feeds PV straight from registers (16x16x16 B-operand).
// Load balance (this round): block blockIdx.x = qt handles the q-tile PAIR
// (qt, 31-qt) at 64-row granularity. PV work = (qt+1)+(32-qt) ~ 33 tiles,
// UNIFORM across all 512 blocks (was 2..32 -> tail makespan). Each wave:
// 16 low-q rows (g=0) + 16 high-q rows (g=1); shared K/V frag reads.
__global__ __launch_bounds__(256)
void attn_fused(const half_t* __restrict__ Qb, const half_t* __restrict__ Kb,
                const half_t* __restrict__ Vtb, half_t* __restrict__ AOut)
{
    const int qt = blockIdx.x;   // 0..15: q tiles qt (low) and 31-qt (high)
    const int bh = blockIdx.y;   // 0..31 (b*16+h)

    __shared__ __align__(16) half_t Ksh[2][64][64];   // [buf][key][d], chunk-swizzled
    __shared__ __align__(16) half_t Vsh[2][64][72];   // [buf][d][key], padded

    const int t = threadIdx.x;
    const int wave = t >> 6, lane = t & 63, quad = lane >> 4, l16 = lane & 15;

    // per-wave group base q rows: g=0 low tile, g=1 high tile
    const int qb0 = qt * 64 + wave * 16;
    const int qb1 = (31 - qt) * 64 + wave * 16;

    // Q fragments for both groups (B-operand layout of 16x16x32)
    half8 qf[2][2];
    {
        const half_t* Qp0 = Qb + ((size_t)bh * SEQ + qb0 + l16) * DH + quad * 8;
        qf[0][0] = *(const half8*)Qp0;
        qf[0][1] = *(const half8*)(Qp0 + 32);
        const half_t* Qp1 = Qb + ((size_t)bh * SEQ + qb1 + l16) * DH + quad * 8;
        qf[1][0] = *(const half8*)Qp1;
        qf[1][1] = *(const half8*)(Qp1 + 32);
    }

    float4v o[2][4] = {};    // O^T accum per group
    float lsum[2] = {0.f, 0.f};

    // K DMA staging (wave covers 16 key rows; XOR chunk swizzle)
    const int krow = lane >> 3, kpos = lane & 7;
    const int kchunk = kpos ^ krow;
    const half_t* Ksrc0 = Kb + ((size_t)bh * SEQ + wave * 16     + krow) * DH + kchunk * 8;
    const half_t* Ksrc1 = Kb + ((size_t)bh * SEQ + wave * 16 + 8 + krow) * DH + kchunk * 8;
    const int ko1 = ((quad ^ (l16 & 7)) * 8);
    const int ko2 = ko1 ^ 32;

    // V staging (register path, full 64x64 tile)
    const int sr  = t >> 2;          // 0..63 (d)
    const int scc = (t & 3) * 16;    // 0,16,32,48 (key)
    const half_t* Vg = Vtb + ((size_t)bh * DH + sr) * SEQ + scc;

    // prologue: tile 0 into buffer 0 (kt=0 always needed for V: 0 <= 31-qt)
    glds16(Ksrc0, &Ksh[0][wave * 16][0]);
    glds16(Ksrc1, &Ksh[0][wave * 16 + 8][0]);
    *(uint4*)&Vsh[0][sr][scc]     = *(const uint4*)(Vg);
    *(uint4*)&Vsh[0][sr][scc + 8] = *(const uint4*)(Vg + 8);
    __syncthreads();

    const int ktop = 31 - qt;   // highest V/PV tile index for this block
    for (int kt = 0; kt < SEQ / 64; ++kt) {
        const int cur = kt & 1, nxt = cur ^ 1;
        const bool have_next = (kt + 1 < SEQ / 64);
        const bool next_v    = (kt + 1 <= ktop);

        uint4 va, vb;
        if (have_next) {
            const half_t* Kn = Ksrc0 + (size_t)(kt + 1) * 64 * DH;
            glds16(Kn,          &Ksh[nxt][wave * 16][0]);
            glds16(Kn + 8 * DH, &Ksh[nxt][wave * 16 + 8][0]);
            if (next_v) {
                const half_t* Vgk = Vg + (kt + 1) * 64;
                va = *(const uint4*)(Vgk);
                vb = *(const uint4*)(Vgk + 8);
            }
        }

        // S^T: one kf read pair serves BOTH q groups
        float4v sc[2][4];
#pragma unroll
        for (int nb = 0; nb < 4; ++nb) {
            const half_t* kp = &Ksh[cur][nb * 16 + l16][0];
            half8 kf0 = *(const half8*)(kp + ko1);
            half8 kf1 = *(const half8*)(kp + ko2);
#pragma unroll
            for (int g = 0; g < 2; ++g) {
                float4v a = {};
                a = __builtin_amdgcn_mfma_f32_16x16x32_f16(kf0, qf[g][0], a, 0, 0, 0);
                a = __builtin_amdgcn_mfma_f32_16x16x32_f16(kf1, qf[g][1], a, 0, 0, 0);
                sc[g][nb] = a;
            }
        }

        // P = exp2(sc); per-lane partial denominators (all keys, both groups)
#pragma unroll
        for (int g = 0; g < 2; ++g)
#pragma unroll
            for (int nb = 0; nb < 4; ++nb)
#pragma unroll
                for (int r = 0; r < 4; ++r) {
                    float e = __builtin_amdgcn_exp2f(sc[g][nb][r]);
                    sc[g][nb][r] = e;
                    lsum[g] += e;
                }

        const int kbase = kt * 64;
        const bool act1 = (kbase <= qb1 + 15);   // high group has unmasked keys
        const bool act0 = (kbase <= qb0 + 15);   // low group (act0 => act1)
        if (act1) {
            // post-softmax causal zeroing on straddle tiles
            if (kbase + 63 > qb1) {
#pragma unroll
                for (int nb = 0; nb < 4; ++nb)
#pragma unroll
                    for (int r = 0; r < 4; ++r)
                        if (kbase + nb * 16 + quad * 4 + r > qb1 + l16) sc[1][nb][r] = 0.f;
            }
            if (act0 && (kbase + 63 > qb0)) {
#pragma unroll
                for (int nb = 0; nb < 4; ++nb)
#pragma unroll
                    for (int r = 0; r < 4; ++r)
                        if (kbase + nb * 16 + quad * 4 + r > qb0 + l16) sc[0][nb][r] = 0.f;
            }
            half4 pf[2][4];
#pragma unroll
            for (int nb = 0; nb < 4; ++nb) {
                union { fp16x2 v2[2]; half4 v4; } u1;
                u1.v2[0] = __builtin_amdgcn_cvt_pkrtz(sc[1][nb][0], sc[1][nb][1]);
                u1.v2[1] = __builtin_amdgcn_cvt_pkrtz(sc[1][nb][2], sc[1][nb][3]);
                pf[1][nb] = u1.v4;
            }
            if (act0) {
#pragma unroll
                for (int nb = 0; nb < 4; ++nb) {
                    union { fp16x2 v2[2]; half4 v4; } u0;
                    u0.v2[0] = __builtin_amdgcn_cvt_pkrtz(sc[0][nb][0], sc[0][nb][1]);
                    u0.v2[1] = __builtin_amdgcn_cvt_pkrtz(sc[0][nb][2], sc[0][nb][3]);
                    pf[0][nb] = u0.v4;
                }
            }
            // one vf read feeds both groups' PV MFMAs
#pragma unroll
            for (int md = 0; md < 4; ++md)
#pragma unroll
                for (int nb = 0; nb < 4; ++nb) {
                    half4 vf = *(const half4*)&Vsh[cur][md * 16 + l16][nb * 16 + quad * 4];
                    o[1][md] = __builtin_amdgcn_mfma_f32_16x16x16f16(vf, pf[1][nb], o[1][md], 0, 0, 0);
                    if (act0)
                        o[0][md] = __builtin_amdgcn_mfma_f32_16x16x16f16(vf, pf[0][nb], o[0][md], 0, 0, 0);
                }
        }

        if (have_next && next_v) {
            *(uint4*)&Vsh[nxt][sr][scc]     = va;
            *(uint4*)&Vsh[nxt][sr][scc + 8] = vb;
        }
        __syncthreads();   // single barrier per key tile
    }

    // epilogue: per group, denominator (2 shuffles) + O^T transpose via LDS
    const int b = bh >> 4, h = bh & 15;
    const int orow = lane >> 2, occ = (lane & 3) * 16;
#pragma unroll
    for (int g = 0; g < 2; ++g) {
        float rs = lsum[g];
        rs += __shfl_xor(rs, 16, 64);
        rs += __shfl_xor(rs, 32, 64);
        const float inv = 1.0f / rs;
        half_t (*Osh)[72] = (half_t(*)[72]) & Vsh[g][wave * 16][0];   // wave-private 16x72
#pragma unroll
        for (int md = 0; md < 4; ++md)
#pragma unroll
            for (int r = 0; r < 4; ++r)
                Osh[l16][md * 16 + quad * 4 + r] = (half_t)(o[g][md][r] * inv);
        __asm__ volatile("s_waitcnt lgkmcnt(0)" ::: "memory");
        uint4 o0 = *(const uint4*)&Osh[orow][occ];
        uint4 o1 = *(const uint4*)&Osh[orow][occ + 8];
        const int s = ((g == 0) ? qt : (31 - qt)) * 64 + wave * 16 + orow;
        half_t* dst = AOut + ((size_t)(b * SEQ + s)) * HDIM + h * DH + occ;
        *(uint4*)dst       = o0;
        *(uint4*)(dst + 8) = o1;
    }
}

// ---------------- launch ----------------
extern "C" void kernel_launch(void* const* d_in, const int* in_sizes, int n_in,
                              void* d_out, int out_size, void* d_ws, size_t ws_size,
                              hipStream_t stream)
{
    const float* x  = (const float*)d_in[0];
    const float* wq = (const float*)d_in[1];
    const float* wk = (const float*)d_in[2];
    const float* wv = (const float*)d_in[3];
    const float* wo = (const float*)d_in[4];
    float* out = (float*)d_out;

    char* ws = (char*)d_ws;
    size_t off = 0;
    auto alloc = [&](size_t bytes) -> void* {
        void* p = ws + off;
        off += (bytes + 255) & ~(size_t)255;
        return p;
    };
    half_t* xh   = (half_t*)alloc((size_t)MTOT * HDIM * 2);   // 8 MB
    half_t* wqh  = (half_t*)alloc((size_t)HDIM * HDIM * 2);   // 2 MB
    half_t* wkh  = (half_t*)alloc((size_t)HDIM * HDIM * 2);
    half_t* wvh  = (half_t*)alloc((size_t)HDIM * HDIM * 2);
    half_t* woh  = (half_t*)alloc((size_t)HDIM * HDIM * 2);
    half_t* Qb   = (half_t*)alloc((size_t)BHTOT * SEQ * DH * 2);  // 8 MB
    half_t* Kb   = (half_t*)alloc((size_t)BHTOT * SEQ * DH * 2);
    half_t* Vtb  = (half_t*)alloc((size_t)BHTOT * SEQ * DH * 2);
    half_t* ah   = (half_t*)alloc((size_t)MTOT * HDIM * 2);       // 8 MB
    float2* rope = (float2*)alloc((size_t)SEQ * 32 * sizeof(float2));

    prep<<<8448, 256, 0, stream>>>(x, wq, wk, wv, wo, xh, wqh, wkh, wvh, woh, rope);

    // Q, K, V in one launch (grid.z selects weight + epilogue)
    gemm_qkv<<<dim3(32, 8, 3), 256, 0, stream>>>(xh, wqh, wkh, wvh,
                                                 Qb, Kb, Vtb, nullptr, rope, 0);
    attn_fused<<<dim3(16, 32), 256, 0, stream>>>(Qb, Kb, Vtb, ah);
    // out = attn @ w_o^T, fp32 epilogue
    gemm_qkv<<<dim3(32, 8, 1), 256, 0, stream>>>(ah, woh, woh, woh,
                                                 nullptr, nullptr, nullptr, out, rope, 3);
}

// Round 9
// 195.304 us; speedup vs baseline: 1.0889x; 1.0889x over previous
//
#include <hip/hip_runtime.h>
#include <math.h>

#define SEQ   2048
#define HDIM  1024
#define NH    16
#define DH    64
#define MTOT  4096   // B*S
#define BHTOT 32     // B*NH

typedef _Float16 half_t;
typedef __attribute__((ext_vector_type(2))) __fp16 fp16x2;
typedef __attribute__((ext_vector_type(4))) _Float16 half4;
typedef __attribute__((ext_vector_type(8))) _Float16 half8;
typedef __attribute__((ext_vector_type(4))) float float4v;

// async global->LDS DMA, 16 B per lane; LDS dest = wave-uniform base + lane*16
typedef __attribute__((address_space(1))) const unsigned int guint;
typedef __attribute__((address_space(3))) unsigned int luint;
__device__ __forceinline__ void glds16(const half_t* g, half_t* l) {
    __builtin_amdgcn_global_load_lds((guint*)g, (luint*)l, 16, 0, 0);
}

// ---------------- fused prologue: 5 fp32->fp16 casts + rope table ----------------
__global__ __launch_bounds__(256)
void prep(const float* __restrict__ x,  const float* __restrict__ wq,
          const float* __restrict__ wk, const float* __restrict__ wv,
          const float* __restrict__ wo,
          half_t* __restrict__ xh,  half_t* __restrict__ wqh,
          half_t* __restrict__ wkh, half_t* __restrict__ wvh,
          half_t* __restrict__ woh, float2* __restrict__ rope)
{
    const int bid = blockIdx.x;
    if (bid < 8192) {
        int i = bid * 256 + threadIdx.x;
        const float* s; half_t* d;
        if (i < 1048576) { s = x; d = xh; }
        else {
            int j = i - 1048576;
            int w = j >> 18; i = j & 262143;
            s = (w == 0) ? wq : (w == 1) ? wk : (w == 2) ? wv : wo;
            d = (w == 0) ? wqh : (w == 1) ? wkh : (w == 2) ? wvh : woh;
        }
        float4 v = ((const float4*)s)[i];
        union { half_t h[4]; uint2 u; } tmp;
        tmp.h[0] = (half_t)v.x; tmp.h[1] = (half_t)v.y;
        tmp.h[2] = (half_t)v.z; tmp.h[3] = (half_t)v.w;
        ((uint2*)d)[i] = tmp.u;
    } else {
        int tt = (bid - 8192) * 256 + threadIdx.x;   // 0 .. SEQ*32-1
        int s = tt >> 5, j = tt & 31;
        float inv = powf(10000.0f, -(float)j / 32.0f);
        float ang = (float)s * inv;
        rope[tt] = make_float2(cosf(ang), sinf(ang));
    }
}

// ---------------- GEMM: C = A(4096x1024,f16) * W^T(1024x1024,f16) ----------------
// m97 structure: global_load_lds width-16 staging, unpadded [128][32] LDS.
// mode 0/1 epilogue: rope in registers -> per-wave LDS bounce -> uint4 stores.
__global__ __launch_bounds__(256)
void gemm_qkv(const half_t* __restrict__ A,
              const half_t* __restrict__ w0, const half_t* __restrict__ w1,
              const half_t* __restrict__ w2,
              half_t* __restrict__ Qb, half_t* __restrict__ Kb,
              half_t* __restrict__ Vtb, float* __restrict__ outF,
              const float2* __restrict__ rope, int mode_base)
{
    const int mode = mode_base + blockIdx.z;
    const half_t* Bw = (mode == 1) ? w1 : (mode == 2) ? w2 : w0;

    __shared__ __align__(16) half_t Ash[128][32];
    __shared__ __align__(16) half_t Bsh[128][32];
    __shared__ __align__(16) half_t Esh[4][32][72];   // epilogue bounce (per-wave 32x64, padded)

    const int t    = threadIdx.x;
    const int lane = t & 63;
    const int wave = t >> 6;
    const int quad = lane >> 4;
    const int l16  = lane & 15;
    const int wr   = (wave >> 1) * 64;
    const int wc   = (wave & 1) * 64;
    const int bm   = blockIdx.x, bn = blockIdx.y;

    const int srow = lane >> 2, spos = lane & 3;
    const half_t* Asrc0 = A  + (size_t)(bm * 128 + wave * 32      + srow) * HDIM + spos * 8;
    const half_t* Asrc1 = A  + (size_t)(bm * 128 + wave * 32 + 16 + srow) * HDIM + spos * 8;
    const half_t* Bsrc0 = Bw + (size_t)(bn * 128 + wave * 32      + srow) * HDIM + spos * 8;
    const half_t* Bsrc1 = Bw + (size_t)(bn * 128 + wave * 32 + 16 + srow) * HDIM + spos * 8;
    half_t* Adst0 = &Ash[wave * 32][0];
    half_t* Adst1 = &Ash[wave * 32 + 16][0];
    half_t* Bdst0 = &Bsh[wave * 32][0];
    half_t* Bdst1 = &Bsh[wave * 32 + 16][0];

    float4v acc[4][4] = {};

    for (int kt = 0; kt < HDIM / 32; ++kt) {
        glds16(Asrc0, Adst0);
        glds16(Asrc1, Adst1);
        glds16(Bsrc0, Bdst0);
        glds16(Bsrc1, Bdst1);
        Asrc0 += 32; Asrc1 += 32; Bsrc0 += 32; Bsrc1 += 32;
        __syncthreads();
        half8 af[4], bf[4];
#pragma unroll
        for (int mb = 0; mb < 4; ++mb) af[mb] = *(const half8*)&Ash[wr + mb * 16 + l16][quad * 8];
#pragma unroll
        for (int nb = 0; nb < 4; ++nb) bf[nb] = *(const half8*)&Bsh[wc + nb * 16 + l16][quad * 8];
#pragma unroll
        for (int mb = 0; mb < 4; ++mb)
#pragma unroll
            for (int nb = 0; nb < 4; ++nb)
                acc[mb][nb] = __builtin_amdgcn_mfma_f32_16x16x32_f16(af[mb], bf[nb], acc[mb][nb], 0, 0, 0);
        __syncthreads();
    }

    if (mode == 3) {
#pragma unroll
        for (int mb = 0; mb < 4; ++mb)
#pragma unroll
            for (int nb = 0; nb < 4; ++nb) {
                int row0 = bm * 128 + wr + mb * 16 + quad * 4;
                int col  = bn * 128 + wc + nb * 16 + l16;
#pragma unroll
                for (int r = 0; r < 4; ++r)
                    outF[(size_t)(row0 + r) * HDIM + col] = acc[mb][nb][r];
            }
        return;
    }
    if (mode == 2) {  // V, transposed store: Vtb[bh][d][s]
#pragma unroll
        for (int mb = 0; mb < 4; ++mb)
#pragma unroll
            for (int nb = 0; nb < 4; ++nb) {
                int row0 = bm * 128 + wr + mb * 16 + quad * 4;
                int col  = bn * 128 + wc + nb * 16 + l16;
                int b = row0 >> 11, s0 = row0 & 2047;
                int h = col >> 6,  dd = col & 63;
                union { half_t h4[4]; uint2 u; } tmp;
#pragma unroll
                for (int r = 0; r < 4; ++r) tmp.h4[r] = (half_t)acc[mb][nb][r];
                *(uint2*)&Vtb[((size_t)((b * NH + h) * DH + dd)) * SEQ + s0] = tmp.u;
            }
        return;
    }
    // mode 0 (Q: rope + scale) / mode 1 (K: rope) — LDS bounce, vectorized stores
    {
        half_t* Ob = (mode == 0) ? Qb : Kb;
        const float scl = (mode == 0) ? 0.125f * 1.44269504088896f : 1.0f;
        const int h = (bn * 128 + wc) >> 6;   // wave's 64 cols = one head
#pragma unroll
        for (int mh = 0; mh < 2; ++mh) {
#pragma unroll
            for (int mb2 = 0; mb2 < 2; ++mb2) {
                const int mb = mh * 2 + mb2;
                const int row0 = bm * 128 + wr + mb * 16 + quad * 4;
#pragma unroll
                for (int nb = 0; nb < 4; ++nb) {
                    const int dd = nb * 16 + l16;
                    const int jj = dd >> 1;
#pragma unroll
                    for (int r = 0; r < 4; ++r) {
                        float v  = acc[mb][nb][r];
                        float vp = __shfl_xor(v, 1, 64);   // partner column (dd^1)
                        int s = (row0 + r) & 2047;
                        float2 cs = rope[s * 32 + jj];
                        float res = ((dd & 1) == 0) ? (v * cs.x - vp * cs.y)
                                                    : (vp * cs.y + v * cs.x);
                        Esh[wave][mb2 * 16 + quad * 4 + r][dd] = (half_t)(res * scl);
                    }
                }
            }
            __asm__ volatile("s_waitcnt lgkmcnt(0)" ::: "memory");  // wave-private region
#pragma unroll
            for (int c = 0; c < 4; ++c) {
                int uidx = c * 64 + lane;
                int row = uidx >> 3, ch = uidx & 7;
                uint4 v = *(const uint4*)&Esh[wave][row][ch * 8];
                int sg = bm * 128 + wr + mh * 32 + row;
                int b = sg >> 11, s = sg & 2047;
                *(uint4*)&Ob[((size_t)((b * NH + h) * SEQ + s)) * DH + ch * 8] = v;
            }
            // per-wave DS ops are in-order: reads above complete before next mh's writes
        }
    }
}

// ---------------- fused attention ----------------
// Reference semantics: softmax over ALL keys, THEN causal zeroing, NO renorm.
// S^T = K*Q^T; P^T feeds PV straight from registers (16x16x16 B-operand).
// Balance (this round): 512-thread blocks, 8 waves. Waves 0-3 = q-tile j
// (light), waves 4-7 = q-tile 15-j (heavy) -> per-block work EXACTLY uniform
// (32 QK + 34 PV group-tiles), no dispatch-order assumption. Each wave keeps
// 32 CONTIGUOUS q rows (2 groups of 16) so one K/V frag read still serves
// both groups. K staged by waves 0-3 (DMA), V by waves 4-7: staging per unit
// work halves vs round 7.
__global__ __launch_bounds__(512)
void attn_fused(const half_t* __restrict__ Qb, const half_t* __restrict__ Kb,
                const half_t* __restrict__ Vtb, half_t* __restrict__ AOut)
{
    const int jb = blockIdx.x;   // 0..7: q-tile pair (jb, 15-jb) at 128-row granularity
    const int bh = blockIdx.y;   // 0..31 (b*16+h)

    __shared__ __align__(16) half_t Ksh[2][64][64];   // [buf][key][d], chunk-swizzled
    __shared__ __align__(16) half_t Vsh[2][64][72];   // [buf][d][key], padded

    const int t = threadIdx.x;
    const int wave = t >> 6, lane = t & 63, quad = lane >> 4, l16 = lane & 15;
    const int unit = wave >> 2, wl = wave & 3;
    const int qtile = unit ? (15 - jb) : jb;
    const int q0 = qtile * 128 + wl * 32;     // wave's first q row
    const int ktop = 2 * (15 - jb) + 1;       // V staging bound (heavy unit governs)

    // Q fragments for both 16-row groups (B-operand layout of 16x16x32)
    half8 qf[2][2];
#pragma unroll
    for (int g = 0; g < 2; ++g) {
        const half_t* Qp = Qb + ((size_t)bh * SEQ + q0 + g * 16 + l16) * DH + quad * 8;
        qf[g][0] = *(const half8*)Qp;
        qf[g][1] = *(const half8*)(Qp + 32);
    }

    float4v o[2][4] = {};    // O^T accum per group
    float lsum[2] = {0.f, 0.f};

    // K DMA staging (waves 0-3 only; wl*16 rows; XOR chunk swizzle)
    const int krow = lane >> 3, kpos = lane & 7;
    const int kchunk = kpos ^ krow;
    const half_t* Ksrc0 = Kb + ((size_t)bh * SEQ + wl * 16     + krow) * DH + kchunk * 8;
    const half_t* Ksrc1 = Kb + ((size_t)bh * SEQ + wl * 16 + 8 + krow) * DH + kchunk * 8;
    const int ko1 = ((quad ^ (l16 & 7)) * 8);
    const int ko2 = ko1 ^ 32;

    // V staging (waves 4-7 only; register path, full 64x64 tile)
    const int tv  = t & 255;
    const int sr  = tv >> 2;          // 0..63 (d)
    const int scc = (tv & 3) * 16;    // 0,16,32,48 (key)
    const half_t* Vg = Vtb + ((size_t)bh * DH + sr) * SEQ + scc;

    // prologue: tile 0 into buffer 0
    if (unit == 0) {
        glds16(Ksrc0, &Ksh[0][wl * 16][0]);
        glds16(Ksrc1, &Ksh[0][wl * 16 + 8][0]);
    } else {
        *(uint4*)&Vsh[0][sr][scc]     = *(const uint4*)(Vg);
        *(uint4*)&Vsh[0][sr][scc + 8] = *(const uint4*)(Vg + 8);
    }
    __syncthreads();

    for (int kt = 0; kt < SEQ / 64; ++kt) {
        const int cur = kt & 1, nxt = cur ^ 1;
        const bool have_next = (kt + 1 < SEQ / 64);
        const bool next_v    = (kt + 1 <= ktop);

        uint4 va, vb;
        if (unit == 0) {
            if (have_next) {
                const half_t* Kn = Ksrc0 + (size_t)(kt + 1) * 64 * DH;
                glds16(Kn,          &Ksh[nxt][wl * 16][0]);
                glds16(Kn + 8 * DH, &Ksh[nxt][wl * 16 + 8][0]);
            }
        } else if (have_next && next_v) {
            const half_t* Vgk = Vg + (kt + 1) * 64;
            va = *(const uint4*)(Vgk);
            vb = *(const uint4*)(Vgk + 8);
        }

        // S^T: one kf read pair serves BOTH q groups
        float4v sc[2][4];
#pragma unroll
        for (int nb = 0; nb < 4; ++nb) {
            const half_t* kp = &Ksh[cur][nb * 16 + l16][0];
            half8 kf0 = *(const half8*)(kp + ko1);
            half8 kf1 = *(const half8*)(kp + ko2);
#pragma unroll
            for (int g = 0; g < 2; ++g) {
                float4v a = {};
                a = __builtin_amdgcn_mfma_f32_16x16x32_f16(kf0, qf[g][0], a, 0, 0, 0);
                a = __builtin_amdgcn_mfma_f32_16x16x32_f16(kf1, qf[g][1], a, 0, 0, 0);
                sc[g][nb] = a;
            }
        }

        // P = exp2(sc); per-lane partial denominators
#pragma unroll
        for (int g = 0; g < 2; ++g)
#pragma unroll
            for (int nb = 0; nb < 4; ++nb)
#pragma unroll
                for (int r = 0; r < 4; ++r) {
                    float e = __builtin_amdgcn_exp2f(sc[g][nb][r]);
                    sc[g][nb][r] = e;
                    lsum[g] += e;
                }

        const int kbase = kt * 64;
        if (kbase <= q0 + 31) {   // wave-uniform: at least one unmasked key
            if (kbase + 63 > q0) {   // straddle: element-wise post-softmax zeroing
#pragma unroll
                for (int g = 0; g < 2; ++g) {
                    int qg = q0 + g * 16 + l16;
#pragma unroll
                    for (int nb = 0; nb < 4; ++nb)
#pragma unroll
                        for (int r = 0; r < 4; ++r)
                            if (kbase + nb * 16 + quad * 4 + r > qg) sc[g][nb][r] = 0.f;
                }
            }
            half4 pf[2][4];
#pragma unroll
            for (int g = 0; g < 2; ++g)
#pragma unroll
                for (int nb = 0; nb < 4; ++nb) {
                    union { fp16x2 v2[2]; half4 v4; } u;
                    u.v2[0] = __builtin_amdgcn_cvt_pkrtz(sc[g][nb][0], sc[g][nb][1]);
                    u.v2[1] = __builtin_amdgcn_cvt_pkrtz(sc[g][nb][2], sc[g][nb][3]);
                    pf[g][nb] = u.v4;
                }
            // one vf read feeds BOTH q groups' PV MFMAs
#pragma unroll
            for (int md = 0; md < 4; ++md)
#pragma unroll
                for (int nb = 0; nb < 4; ++nb) {
                    half4 vf = *(const half4*)&Vsh[cur][md * 16 + l16][nb * 16 + quad * 4];
                    o[0][md] = __builtin_amdgcn_mfma_f32_16x16x16f16(vf, pf[0][nb], o[0][md], 0, 0, 0);
                    o[1][md] = __builtin_amdgcn_mfma_f32_16x16x16f16(vf, pf[1][nb], o[1][md], 0, 0, 0);
                }
        }

        if (unit == 1 && have_next && next_v) {
            *(uint4*)&Vsh[nxt][sr][scc]     = va;
            *(uint4*)&Vsh[nxt][sr][scc + 8] = vb;
        }
        __syncthreads();   // single barrier per key tile
    }

    // epilogue: per group, denominator (2 shuffles) + O^T transpose via LDS.
    // Per-wave scratch: waves 0-3 carve Ksh, waves 4-7 carve Vsh (all compute
    // done past the final barrier; per-wave DS ops are in-order so the region
    // can be reused across g).
    const int b = bh >> 4, h = bh & 15;
    const int orow = lane >> 2, occ = (lane & 3) * 16;
    half_t* scr = unit ? ((half_t*)Vsh + wl * 1152) : ((half_t*)Ksh + wl * 1152);
    half_t (*Osh)[72] = (half_t(*)[72])scr;   // 16 x 72
#pragma unroll
    for (int g = 0; g < 2; ++g) {
        float rs = lsum[g];
        rs += __shfl_xor(rs, 16, 64);
        rs += __shfl_xor(rs, 32, 64);
        const float inv = 1.0f / rs;
#pragma unroll
        for (int md = 0; md < 4; ++md)
#pragma unroll
            for (int r = 0; r < 4; ++r)
                Osh[l16][md * 16 + quad * 4 + r] = (half_t)(o[g][md][r] * inv);
        __asm__ volatile("s_waitcnt lgkmcnt(0)" ::: "memory");
        uint4 o0 = *(const uint4*)&Osh[orow][occ];
        uint4 o1 = *(const uint4*)&Osh[orow][occ + 8];
        const int s = q0 + g * 16 + orow;
        half_t* dst = AOut + ((size_t)(b * SEQ + s)) * HDIM + h * DH + occ;
        *(uint4*)dst       = o0;
        *(uint4*)(dst + 8) = o1;
    }
}

// ---------------- launch ----------------
extern "C" void kernel_launch(void* const* d_in, const int* in_sizes, int n_in,
                              void* d_out, int out_size, void* d_ws, size_t ws_size,
                              hipStream_t stream)
{
    const float* x  = (const float*)d_in[0];
    const float* wq = (const float*)d_in[1];
    const float* wk = (const float*)d_in[2];
    const float* wv = (const float*)d_in[3];
    const float* wo = (const float*)d_in[4];
    float* out = (float*)d_out;

    char* ws = (char*)d_ws;
    size_t off = 0;
    auto alloc = [&](size_t bytes) -> void* {
        void* p = ws + off;
        off += (bytes + 255) & ~(size_t)255;
        return p;
    };
    half_t* xh   = (half_t*)alloc((size_t)MTOT * HDIM * 2);   // 8 MB
    half_t* wqh  = (half_t*)alloc((size_t)HDIM * HDIM * 2);   // 2 MB
    half_t* wkh  = (half_t*)alloc((size_t)HDIM * HDIM * 2);
    half_t* wvh  = (half_t*)alloc((size_t)HDIM * HDIM * 2);
    half_t* woh  = (half_t*)alloc((size_t)HDIM * HDIM * 2);
    half_t* Qb   = (half_t*)alloc((size_t)BHTOT * SEQ * DH * 2);  // 8 MB
    half_t* Kb   = (half_t*)alloc((size_t)BHTOT * SEQ * DH * 2);
    half_t* Vtb  = (half_t*)alloc((size_t)BHTOT * SEQ * DH * 2);
    half_t* ah   = (half_t*)alloc((size_t)MTOT * HDIM * 2);       // 8 MB
    float2* rope = (float2*)alloc((size_t)SEQ * 32 * sizeof(float2));

    prep<<<8448, 256, 0, stream>>>(x, wq, wk, wv, wo, xh, wqh, wkh, wvh, woh, rope);

    // Q, K, V in one launch (grid.z selects weight + epilogue)
    gemm_qkv<<<dim3(32, 8, 3), 256, 0, stream>>>(xh, wqh, wkh, wvh,
                                                 Qb, Kb, Vtb, nullptr, rope, 0);
    attn_fused<<<dim3(8, 32), 512, 0, stream>>>(Qb, Kb, Vtb, ah);
    // out = attn @ w_o^T, fp32 epilogue
    gemm_qkv<<<dim3(32, 8, 1), 256, 0, stream>>>(ah, woh, woh, woh,
                                                 nullptr, nullptr, nullptr, out, rope, 3);
}

// Round 10
// 193.493 us; speedup vs baseline: 1.0991x; 1.0094x over previous
//
#include <hip/hip_runtime.h>
#include <math.h>

#define SEQ   2048
#define HDIM  1024
#define NH    16
#define DH    64
#define MTOT  4096   // B*S
#define BHTOT 32     // B*NH

typedef _Float16 half_t;
typedef __attribute__((ext_vector_type(2))) __fp16 fp16x2;
typedef __attribute__((ext_vector_type(4))) _Float16 half4;
typedef __attribute__((ext_vector_type(8))) _Float16 half8;
typedef __attribute__((ext_vector_type(4))) float float4v;

// async global->LDS DMA, 16 B per lane; LDS dest = wave-uniform base + lane*16
typedef __attribute__((address_space(1))) const unsigned int guint;
typedef __attribute__((address_space(3))) unsigned int luint;
__device__ __forceinline__ void glds16(const half_t* g, half_t* l) {
    __builtin_amdgcn_global_load_lds((guint*)g, (luint*)l, 16, 0, 0);
}

// ---------------- fused prologue: 5 fp32->fp16 casts + rope table ----------------
__global__ __launch_bounds__(256)
void prep(const float* __restrict__ x,  const float* __restrict__ wq,
          const float* __restrict__ wk, const float* __restrict__ wv,
          const float* __restrict__ wo,
          half_t* __restrict__ xh,  half_t* __restrict__ wqh,
          half_t* __restrict__ wkh, half_t* __restrict__ wvh,
          half_t* __restrict__ woh, float2* __restrict__ rope)
{
    const int bid = blockIdx.x;
    if (bid < 8192) {
        int i = bid * 256 + threadIdx.x;
        const float* s; half_t* d;
        if (i < 1048576) { s = x; d = xh; }
        else {
            int j = i - 1048576;
            int w = j >> 18; i = j & 262143;
            s = (w == 0) ? wq : (w == 1) ? wk : (w == 2) ? wv : wo;
            d = (w == 0) ? wqh : (w == 1) ? wkh : (w == 2) ? wvh : woh;
        }
        float4 v = ((const float4*)s)[i];
        union { half_t h[4]; uint2 u; } tmp;
        tmp.h[0] = (half_t)v.x; tmp.h[1] = (half_t)v.y;
        tmp.h[2] = (half_t)v.z; tmp.h[3] = (half_t)v.w;
        ((uint2*)d)[i] = tmp.u;
    } else {
        int tt = (bid - 8192) * 256 + threadIdx.x;   // 0 .. SEQ*32-1
        int s = tt >> 5, j = tt & 31;
        float inv = powf(10000.0f, -(float)j / 32.0f);
        float ang = (float)s * inv;
        rope[tt] = make_float2(cosf(ang), sinf(ang));
    }
}

// ---------------- GEMM: QKV only. C = A(4096x1024,f16) * W^T, 128x128 tiles ----
// m97 structure: global_load_lds width-16 staging, unpadded [128][32] LDS.
// mode 0: -> Qb [bh][s][d] f16, RoPE + 0.125*log2(e) scale
// mode 1: -> Kb [bh][s][d] f16, RoPE
// mode 2: -> Vtb [bh][d][s] f16 (transposed)
// Epilogue (0/1): rope in registers -> per-wave LDS bounce -> uint4 stores.
__global__ __launch_bounds__(256)
void gemm_qkv(const half_t* __restrict__ A,
              const half_t* __restrict__ w0, const half_t* __restrict__ w1,
              const half_t* __restrict__ w2,
              half_t* __restrict__ Qb, half_t* __restrict__ Kb,
              half_t* __restrict__ Vtb,
              const float2* __restrict__ rope)
{
    const int mode = blockIdx.z;
    const half_t* Bw = (mode == 1) ? w1 : (mode == 2) ? w2 : w0;

    __shared__ __align__(16) half_t Ash[128][32];
    __shared__ __align__(16) half_t Bsh[128][32];
    __shared__ __align__(16) half_t Esh[4][32][72];   // epilogue bounce (per-wave 32x64, padded)

    const int t    = threadIdx.x;
    const int lane = t & 63;
    const int wave = t >> 6;
    const int quad = lane >> 4;
    const int l16  = lane & 15;
    const int wr   = (wave >> 1) * 64;
    const int wc   = (wave & 1) * 64;
    const int bm   = blockIdx.x, bn = blockIdx.y;

    const int srow = lane >> 2, spos = lane & 3;
    const half_t* Asrc0 = A  + (size_t)(bm * 128 + wave * 32      + srow) * HDIM + spos * 8;
    const half_t* Asrc1 = A  + (size_t)(bm * 128 + wave * 32 + 16 + srow) * HDIM + spos * 8;
    const half_t* Bsrc0 = Bw + (size_t)(bn * 128 + wave * 32      + srow) * HDIM + spos * 8;
    const half_t* Bsrc1 = Bw + (size_t)(bn * 128 + wave * 32 + 16 + srow) * HDIM + spos * 8;
    half_t* Adst0 = &Ash[wave * 32][0];
    half_t* Adst1 = &Ash[wave * 32 + 16][0];
    half_t* Bdst0 = &Bsh[wave * 32][0];
    half_t* Bdst1 = &Bsh[wave * 32 + 16][0];

    float4v acc[4][4] = {};

    for (int kt = 0; kt < HDIM / 32; ++kt) {
        glds16(Asrc0, Adst0);
        glds16(Asrc1, Adst1);
        glds16(Bsrc0, Bdst0);
        glds16(Bsrc1, Bdst1);
        Asrc0 += 32; Asrc1 += 32; Bsrc0 += 32; Bsrc1 += 32;
        __syncthreads();
        half8 af[4], bf[4];
#pragma unroll
        for (int mb = 0; mb < 4; ++mb) af[mb] = *(const half8*)&Ash[wr + mb * 16 + l16][quad * 8];
#pragma unroll
        for (int nb = 0; nb < 4; ++nb) bf[nb] = *(const half8*)&Bsh[wc + nb * 16 + l16][quad * 8];
#pragma unroll
        for (int mb = 0; mb < 4; ++mb)
#pragma unroll
            for (int nb = 0; nb < 4; ++nb)
                acc[mb][nb] = __builtin_amdgcn_mfma_f32_16x16x32_f16(af[mb], bf[nb], acc[mb][nb], 0, 0, 0);
        __syncthreads();
    }

    if (mode == 2) {  // V, transposed store: Vtb[bh][d][s]
#pragma unroll
        for (int mb = 0; mb < 4; ++mb)
#pragma unroll
            for (int nb = 0; nb < 4; ++nb) {
                int row0 = bm * 128 + wr + mb * 16 + quad * 4;
                int col  = bn * 128 + wc + nb * 16 + l16;
                int b = row0 >> 11, s0 = row0 & 2047;
                int h = col >> 6,  dd = col & 63;
                union { half_t h4[4]; uint2 u; } tmp;
#pragma unroll
                for (int r = 0; r < 4; ++r) tmp.h4[r] = (half_t)acc[mb][nb][r];
                *(uint2*)&Vtb[((size_t)((b * NH + h) * DH + dd)) * SEQ + s0] = tmp.u;
            }
        return;
    }
    // mode 0 (Q: rope + scale) / mode 1 (K: rope) — LDS bounce, vectorized stores
    {
        half_t* Ob = (mode == 0) ? Qb : Kb;
        const float scl = (mode == 0) ? 0.125f * 1.44269504088896f : 1.0f;
        const int h = (bn * 128 + wc) >> 6;   // wave's 64 cols = one head
#pragma unroll
        for (int mh = 0; mh < 2; ++mh) {
#pragma unroll
            for (int mb2 = 0; mb2 < 2; ++mb2) {
                const int mb = mh * 2 + mb2;
                const int row0 = bm * 128 + wr + mb * 16 + quad * 4;
#pragma unroll
                for (int nb = 0; nb < 4; ++nb) {
                    const int dd = nb * 16 + l16;
                    const int jj = dd >> 1;
#pragma unroll
                    for (int r = 0; r < 4; ++r) {
                        float v  = acc[mb][nb][r];
                        float vp = __shfl_xor(v, 1, 64);   // partner column (dd^1)
                        int s = (row0 + r) & 2047;
                        float2 cs = rope[s * 32 + jj];
                        float res = ((dd & 1) == 0) ? (v * cs.x - vp * cs.y)
                                                    : (vp * cs.y + v * cs.x);
                        Esh[wave][mb2 * 16 + quad * 4 + r][dd] = (half_t)(res * scl);
                    }
                }
            }
            __asm__ volatile("s_waitcnt lgkmcnt(0)" ::: "memory");  // wave-private region
#pragma unroll
            for (int c = 0; c < 4; ++c) {
                int uidx = c * 64 + lane;
                int row = uidx >> 3, ch = uidx & 7;
                uint4 v = *(const uint4*)&Esh[wave][row][ch * 8];
                int sg = bm * 128 + wr + mh * 32 + row;
                int b = sg >> 11, s = sg & 2047;
                *(uint4*)&Ob[((size_t)((b * NH + h) * SEQ + s)) * DH + ch * 8] = v;
            }
            // per-wave DS ops are in-order: reads above complete before next mh's writes
        }
    }
}

// ---------------- output GEMM: out(f32) = ah(4096x1024,f16) @ wo^T ----------------
// 64x128 tiles -> grid (64,8) = 512 blocks = 2 blocks/CU (vs 1 for 128x128):
// this kernel was latency-bound at 1 wave/SIMD (169 TF, VALUBusy 11%).
// Lean body: 12 KB LDS, acc[2][4], 3 glds16/iter.
__global__ __launch_bounds__(256)
void gemm_out(const half_t* __restrict__ A, const half_t* __restrict__ W,
              float* __restrict__ outF)
{
    __shared__ __align__(16) half_t Ash[64][32];
    __shared__ __align__(16) half_t Bsh[128][32];

    const int t    = threadIdx.x;
    const int lane = t & 63;
    const int wave = t >> 6;
    const int quad = lane >> 4;
    const int l16  = lane & 15;
    const int wr   = (wave >> 1) * 32;   // M offset within tile
    const int wc   = (wave & 1) * 64;    // N offset
    const int bm   = blockIdx.x, bn = blockIdx.y;

    const int srow = lane >> 2, spos = lane & 3;
    // A: wave w stages rows [w*16, w*16+16)
    const half_t* Asrc  = A + (size_t)(bm * 64 + wave * 16 + srow) * HDIM + spos * 8;
    half_t* Adst = &Ash[wave * 16][0];
    // B: wave w stages rows [w*32, w*32+32)
    const half_t* Bsrc0 = W + (size_t)(bn * 128 + wave * 32      + srow) * HDIM + spos * 8;
    const half_t* Bsrc1 = W + (size_t)(bn * 128 + wave * 32 + 16 + srow) * HDIM + spos * 8;
    half_t* Bdst0 = &Bsh[wave * 32][0];
    half_t* Bdst1 = &Bsh[wave * 32 + 16][0];

    float4v acc[2][4] = {};

    for (int kt = 0; kt < HDIM / 32; ++kt) {
        glds16(Asrc, Adst);
        glds16(Bsrc0, Bdst0);
        glds16(Bsrc1, Bdst1);
        Asrc += 32; Bsrc0 += 32; Bsrc1 += 32;
        __syncthreads();
        half8 af[2], bf[4];
#pragma unroll
        for (int mb = 0; mb < 2; ++mb) af[mb] = *(const half8*)&Ash[wr + mb * 16 + l16][quad * 8];
#pragma unroll
        for (int nb = 0; nb < 4; ++nb) bf[nb] = *(const half8*)&Bsh[wc + nb * 16 + l16][quad * 8];
#pragma unroll
        for (int mb = 0; mb < 2; ++mb)
#pragma unroll
            for (int nb = 0; nb < 4; ++nb)
                acc[mb][nb] = __builtin_amdgcn_mfma_f32_16x16x32_f16(af[mb], bf[nb], acc[mb][nb], 0, 0, 0);
        __syncthreads();
    }

#pragma unroll
    for (int mb = 0; mb < 2; ++mb)
#pragma unroll
        for (int nb = 0; nb < 4; ++nb) {
            int row0 = bm * 64 + wr + mb * 16 + quad * 4;
            int col  = bn * 128 + wc + nb * 16 + l16;
#pragma unroll
            for (int r = 0; r < 4; ++r)
                outF[(size_t)(row0 + r) * HDIM + col] = acc[mb][nb][r];
        }
}

// ---------------- fused attention ----------------
// Reference semantics: softmax over ALL keys, THEN causal zeroing, NO renorm.
// S^T = K*Q^T; P^T feeds PV straight from registers (16x16x16 B-operand).
// Balance: 512-thread blocks, 8 waves. Waves 0-3 = q-tile j (light),
// waves 4-7 = q-tile 15-j (heavy) -> per-block work exactly uniform.
// Each wave keeps 32 contiguous q rows (2 groups of 16): one K/V frag read
// serves both groups. K staged by waves 0-3 (DMA), V by waves 4-7.
__global__ __launch_bounds__(512)
void attn_fused(const half_t* __restrict__ Qb, const half_t* __restrict__ Kb,
                const half_t* __restrict__ Vtb, half_t* __restrict__ AOut)
{
    const int jb = blockIdx.x;   // 0..7: q-tile pair (jb, 15-jb) at 128-row granularity
    const int bh = blockIdx.y;   // 0..31 (b*16+h)

    __shared__ __align__(16) half_t Ksh[2][64][64];   // [buf][key][d], chunk-swizzled
    __shared__ __align__(16) half_t Vsh[2][64][72];   // [buf][d][key], padded

    const int t = threadIdx.x;
    const int wave = t >> 6, lane = t & 63, quad = lane >> 4, l16 = lane & 15;
    const int unit = wave >> 2, wl = wave & 3;
    const int qtile = unit ? (15 - jb) : jb;
    const int q0 = qtile * 128 + wl * 32;     // wave's first q row
    const int ktop = 2 * (15 - jb) + 1;       // V staging bound (heavy unit governs)

    // Q fragments for both 16-row groups (B-operand layout of 16x16x32)
    half8 qf[2][2];
#pragma unroll
    for (int g = 0; g < 2; ++g) {
        const half_t* Qp = Qb + ((size_t)bh * SEQ + q0 + g * 16 + l16) * DH + quad * 8;
        qf[g][0] = *(const half8*)Qp;
        qf[g][1] = *(const half8*)(Qp + 32);
    }

    float4v o[2][4] = {};    // O^T accum per group
    float lsum[2] = {0.f, 0.f};

    // K DMA staging (waves 0-3 only; XOR chunk swizzle)
    const int krow = lane >> 3, kpos = lane & 7;
    const int kchunk = kpos ^ krow;
    const half_t* Ksrc0 = Kb + ((size_t)bh * SEQ + wl * 16     + krow) * DH + kchunk * 8;
    const half_t* Ksrc1 = Kb + ((size_t)bh * SEQ + wl * 16 + 8 + krow) * DH + kchunk * 8;
    const int ko1 = ((quad ^ (l16 & 7)) * 8);
    const int ko2 = ko1 ^ 32;

    // V staging (waves 4-7 only; register path, full 64x64 tile)
    const int tv  = t & 255;
    const int sr  = tv >> 2;          // 0..63 (d)
    const int scc = (tv & 3) * 16;    // 0,16,32,48 (key)
    const half_t* Vg = Vtb + ((size_t)bh * DH + sr) * SEQ + scc;

    // prologue: tile 0 into buffer 0
    if (unit == 0) {
        glds16(Ksrc0, &Ksh[0][wl * 16][0]);
        glds16(Ksrc1, &Ksh[0][wl * 16 + 8][0]);
    } else {
        *(uint4*)&Vsh[0][sr][scc]     = *(const uint4*)(Vg);
        *(uint4*)&Vsh[0][sr][scc + 8] = *(const uint4*)(Vg + 8);
    }
    __syncthreads();

    for (int kt = 0; kt < SEQ / 64; ++kt) {
        const int cur = kt & 1, nxt = cur ^ 1;
        const bool have_next = (kt + 1 < SEQ / 64);
        const bool next_v    = (kt + 1 <= ktop);

        uint4 va, vb;
        if (unit == 0) {
            if (have_next) {
                const half_t* Kn = Ksrc0 + (size_t)(kt + 1) * 64 * DH;
                glds16(Kn,          &Ksh[nxt][wl * 16][0]);
                glds16(Kn + 8 * DH, &Ksh[nxt][wl * 16 + 8][0]);
            }
        } else if (have_next && next_v) {
            const half_t* Vgk = Vg + (kt + 1) * 64;
            va = *(const uint4*)(Vgk);
            vb = *(const uint4*)(Vgk + 8);
        }

        // S^T: one kf read pair serves BOTH q groups
        float4v sc[2][4];
#pragma unroll
        for (int nb = 0; nb < 4; ++nb) {
            const half_t* kp = &Ksh[cur][nb * 16 + l16][0];
            half8 kf0 = *(const half8*)(kp + ko1);
            half8 kf1 = *(const half8*)(kp + ko2);
#pragma unroll
            for (int g = 0; g < 2; ++g) {
                float4v a = {};
                a = __builtin_amdgcn_mfma_f32_16x16x32_f16(kf0, qf[g][0], a, 0, 0, 0);
                a = __builtin_amdgcn_mfma_f32_16x16x32_f16(kf1, qf[g][1], a, 0, 0, 0);
                sc[g][nb] = a;
            }
        }

        // P = exp2(sc); per-lane partial denominators
#pragma unroll
        for (int g = 0; g < 2; ++g)
#pragma unroll
            for (int nb = 0; nb < 4; ++nb)
#pragma unroll
                for (int r = 0; r < 4; ++r) {
                    float e = __builtin_amdgcn_exp2f(sc[g][nb][r]);
                    sc[g][nb][r] = e;
                    lsum[g] += e;
                }

        const int kbase = kt * 64;
        if (kbase <= q0 + 31) {   // wave-uniform: at least one unmasked key
            if (kbase + 63 > q0) {   // straddle: element-wise post-softmax zeroing
#pragma unroll
                for (int g = 0; g < 2; ++g) {
                    int qg = q0 + g * 16 + l16;
#pragma unroll
                    for (int nb = 0; nb < 4; ++nb)
#pragma unroll
                        for (int r = 0; r < 4; ++r)
                            if (kbase + nb * 16 + quad * 4 + r > qg) sc[g][nb][r] = 0.f;
                }
            }
            half4 pf[2][4];
#pragma unroll
            for (int g = 0; g < 2; ++g)
#pragma unroll
                for (int nb = 0; nb < 4; ++nb) {
                    union { fp16x2 v2[2]; half4 v4; } u;
                    u.v2[0] = __builtin_amdgcn_cvt_pkrtz(sc[g][nb][0], sc[g][nb][1]);
                    u.v2[1] = __builtin_amdgcn_cvt_pkrtz(sc[g][nb][2], sc[g][nb][3]);
                    pf[g][nb] = u.v4;
                }
            // one vf read feeds BOTH q groups' PV MFMAs
#pragma unroll
            for (int md = 0; md < 4; ++md)
#pragma unroll
                for (int nb = 0; nb < 4; ++nb) {
                    half4 vf = *(const half4*)&Vsh[cur][md * 16 + l16][nb * 16 + quad * 4];
                    o[0][md] = __builtin_amdgcn_mfma_f32_16x16x16f16(vf, pf[0][nb], o[0][md], 0, 0, 0);
                    o[1][md] = __builtin_amdgcn_mfma_f32_16x16x16f16(vf, pf[1][nb], o[1][md], 0, 0, 0);
                }
        }

        if (unit == 1 && have_next && next_v) {
            *(uint4*)&Vsh[nxt][sr][scc]     = va;
            *(uint4*)&Vsh[nxt][sr][scc + 8] = vb;
        }
        __syncthreads();   // single barrier per key tile
    }

    // epilogue: per group, denominator (2 shuffles) + O^T transpose via LDS.
    const int b = bh >> 4, h = bh & 15;
    const int orow = lane >> 2, occ = (lane & 3) * 16;
    half_t* scr = unit ? ((half_t*)Vsh + wl * 1152) : ((half_t*)Ksh + wl * 1152);
    half_t (*Osh)[72] = (half_t(*)[72])scr;   // 16 x 72
#pragma unroll
    for (int g = 0; g < 2; ++g) {
        float rs = lsum[g];
        rs += __shfl_xor(rs, 16, 64);
        rs += __shfl_xor(rs, 32, 64);
        const float inv = 1.0f / rs;
#pragma unroll
        for (int md = 0; md < 4; ++md)
#pragma unroll
            for (int r = 0; r < 4; ++r)
                Osh[l16][md * 16 + quad * 4 + r] = (half_t)(o[g][md][r] * inv);
        __asm__ volatile("s_waitcnt lgkmcnt(0)" ::: "memory");
        uint4 o0 = *(const uint4*)&Osh[orow][occ];
        uint4 o1 = *(const uint4*)&Osh[orow][occ + 8];
        const int s = q0 + g * 16 + orow;
        half_t* dst = AOut + ((size_t)(b * SEQ + s)) * HDIM + h * DH + occ;
        *(uint4*)dst       = o0;
        *(uint4*)(dst + 8) = o1;
    }
}

// ---------------- launch ----------------
extern "C" void kernel_launch(void* const* d_in, const int* in_sizes, int n_in,
                              void* d_out, int out_size, void* d_ws, size_t ws_size,
                              hipStream_t stream)
{
    const float* x  = (const float*)d_in[0];
    const float* wq = (const float*)d_in[1];
    const float* wk = (const float*)d_in[2];
    const float* wv = (const float*)d_in[3];
    const float* wo = (const float*)d_in[4];
    float* out = (float*)d_out;

    char* ws = (char*)d_ws;
    size_t off = 0;
    auto alloc = [&](size_t bytes) -> void* {
        void* p = ws + off;
        off += (bytes + 255) & ~(size_t)255;
        return p;
    };
    half_t* xh   = (half_t*)alloc((size_t)MTOT * HDIM * 2);   // 8 MB
    half_t* wqh  = (half_t*)alloc((size_t)HDIM * HDIM * 2);   // 2 MB
    half_t* wkh  = (half_t*)alloc((size_t)HDIM * HDIM * 2);
    half_t* wvh  = (half_t*)alloc((size_t)HDIM * HDIM * 2);
    half_t* woh  = (half_t*)alloc((size_t)HDIM * HDIM * 2);
    half_t* Qb   = (half_t*)alloc((size_t)BHTOT * SEQ * DH * 2);  // 8 MB
    half_t* Kb   = (half_t*)alloc((size_t)BHTOT * SEQ * DH * 2);
    half_t* Vtb  = (half_t*)alloc((size_t)BHTOT * SEQ * DH * 2);
    half_t* ah   = (half_t*)alloc((size_t)MTOT * HDIM * 2);       // 8 MB
    float2* rope = (float2*)alloc((size_t)SEQ * 32 * sizeof(float2));

    prep<<<8448, 256, 0, stream>>>(x, wq, wk, wv, wo, xh, wqh, wkh, wvh, woh, rope);

    // Q, K, V in one launch (grid.z selects weight + epilogue)
    gemm_qkv<<<dim3(32, 8, 3), 256, 0, stream>>>(xh, wqh, wkh, wvh,
                                                 Qb, Kb, Vtb, rope);
    attn_fused<<<dim3(8, 32), 512, 0, stream>>>(Qb, Kb, Vtb, ah);
    // out = attn @ w_o^T: 64x128 tiles, 512 blocks (2/CU) for latency hiding
    gemm_out<<<dim3(64, 8), 256, 0, stream>>>(ah, woh, out);
}